// Round 7
// baseline (255.992 us; speedup 1.0000x reference)
//
#include <hip/hip_runtime.h>

// FrFDConv: per-batch dynamic 3x3 conv, B=16, 16ch->16ch, 512x512 -> 510x510 VALID.
//
// MFMA path (requires ~136 MB workspace):
//   1. transform_kernel: x fp32 NCHW -> x_t f16 NHWC (vectorized, nontemporal x
//      reads), + per-wave pool partial sums
//   2. stage2_kernel:    reduce partials -> pooled -> sigmoid gate -> pack per-batch
//                        weights in MFMA B-fragment layout (K=144 padded to 5*32)
//   3. conv_mfma_kernel: implicit GEMM, mfma_f32_16x16x32_f16. Persistent block
//      over 4 row-tiles with T14 async-STAGE split: issue next tile's global
//      loads to REGISTERS before computing current tile, ds_write after barrier.
//      Staging latency exposed only in prologue (r4/r6 exposed it every tile).
// Fallback (small ws): round-1 fp32 direct conv.

#define BATCH 16
#define CH 16
#define HIN 512
#define WIN 512
#define HOUT 510
#define WOUT 510

typedef _Float16 half8 __attribute__((ext_vector_type(8)));
typedef float f32x4 __attribute__((ext_vector_type(4)));

// K-order kappa = 0..159 (5 chunks x 32): tap t = kappa>>4 (t=9 -> zero pad), chan i = kappa&15.
// MFMA frag (16x16x32): lane l holds k = (l>>4)*8 + j, j=0..7; A row / B col = l&15.

// ---------------- kernel 1: NHWC f16 transform + pool partials -----------------
// grid 4096 (16 b x 256), block 256; thread = 4 consecutive pixels, all 16 ch.
__global__ __launch_bounds__(256) void transform_kernel(const float* __restrict__ x,
                                                        unsigned short* __restrict__ xt,
                                                        float* __restrict__ psum) {
    const int blk = blockIdx.x;
    const int b = blk >> 8, within = blk & 255;
    const int tid = threadIdx.x;
    const int p0 = (within * 256 + tid) * 4;       // pixel base within plane
    const float* xb = x + ((size_t)b << 22);

    f32x4 v[16];
    float s[16];
#pragma unroll
    for (int c = 0; c < 16; ++c) {
        v[c] = __builtin_nontemporal_load((const f32x4*)(xb + ((size_t)c << 18) + p0));
        s[c] = (v[c][0] + v[c][1]) + (v[c][2] + v[c][3]);
    }

    union { _Float16 h[64]; uint4 q[8]; } u;
#pragma unroll
    for (int c = 0; c < 16; ++c) {
        u.h[0 * 16 + c] = (_Float16)v[c][0];
        u.h[1 * 16 + c] = (_Float16)v[c][1];
        u.h[2 * 16 + c] = (_Float16)v[c][2];
        u.h[3 * 16 + c] = (_Float16)v[c][3];
    }
    uint4* dst = (uint4*)(xt + ((size_t)((b << 18) + p0)) * 16);
#pragma unroll
    for (int k = 0; k < 8; ++k) dst[k] = u.q[k];   // cached: conv re-reads x_t

    // wave-level pool partials
#pragma unroll
    for (int c = 0; c < 16; ++c) {
        float r = s[c];
        r += __shfl_xor(r, 1);  r += __shfl_xor(r, 2);  r += __shfl_xor(r, 4);
        r += __shfl_xor(r, 8);  r += __shfl_xor(r, 16); r += __shfl_xor(r, 32);
        s[c] = r;
    }
    if ((tid & 63) == 0) {
        float* ps = psum + (size_t)(b * 1024 + within * 4 + (tid >> 6)) * 16;
#pragma unroll
        for (int c = 0; c < 16; ++c) ps[c] = s[c];
    }
}

// ---------------- kernel 2: pooled -> gate -> weight pack ----------------------
// grid 16 (one block per batch), block 256.
__global__ __launch_bounds__(256) void stage2_kernel(const float* __restrict__ psum,
                                                     const float* __restrict__ attn_w,
                                                     const float* __restrict__ attn_b,
                                                     const float* __restrict__ spectral,
                                                     unsigned short* __restrict__ wpack) {
    const int b = blockIdx.x, t = threadIdx.x;
    const int c = t & 15, m = t >> 4;
    float s = 0.f;
    for (int j = 0; j < 64; ++j) s += psum[((size_t)b * 1024 + m + j * 16) * 16 + c];
    __shared__ float red[256];
    __shared__ float pooled[16];
    __shared__ float pis[64];
    red[t] = s;
    __syncthreads();
    for (int off = 8; off; off >>= 1) {
        if (m < off) red[t] += red[t + off * 16];
        __syncthreads();
    }
    if (t < 16) pooled[t] = red[t] * (1.f / 262144.f);
    __syncthreads();
    if (t < 64) {
        float a = attn_b[t];
#pragma unroll
        for (int c2 = 0; c2 < 16; ++c2) a += pooled[c2] * attn_w[t * 16 + c2];
        pis[t] = 1.f / (1.f + expf(-a));
    }
    __syncthreads();
    for (int e = t; e < 320; e += 256) {
        const int c5 = e >> 6, lane = e & 63;
        const int o = lane & 15, g = lane >> 4;
        union { _Float16 h[8]; uint4 q; } u;
#pragma unroll
        for (int j = 0; j < 8; ++j) {
            const int kap = c5 * 32 + g * 8 + j;
            const int tp = kap >> 4, i = kap & 15;
            float wv = 0.f;
            if (tp < 9) {
                const int ki = tp / 3, kj = tp - ki * 3;
                const int r = i * 3 + ki, cc = o * 3 + kj;
                const float gi = -0.5f + (float)r * (1.f / 47.f);
                const float gj = -0.5f + (float)cc * (1.f / 47.f);
                const float d2 = gi * gi + gj * gj;
                if (d2 < 0.25f) {
                    int gid = (int)(sqrtf(d2) * 128.f);
                    gid = gid < 63 ? gid : 63;
                    wv = spectral[r * 48 + cc] * pis[gid];
                }
            }
            u.h[j] = (_Float16)wv;
        }
        *(uint4*)(wpack + ((size_t)(b * 5 + c5) * 64 + lane) * 8) = u.q;
    }
}

// ---------------- kernel 3: implicit-GEMM conv, async-staged pipeline ----------
// grid 1024: bid = ((b*4 + cg)*16 + g4); block owns row-tiles yg = g4*4 .. g4*4+3.
// Block: 8 waves (512 thr); per tile, wave w computes output row y0+w, 128 cols.
// Pipeline per tile: issue next-tile global loads -> compute current (covers
// latency) -> barrier -> ds_write regs -> barrier.
#define PITCH 4224  // LDS bytes per staged input row (130 px * 32B, padded)
__global__ __launch_bounds__(512) void conv_mfma_kernel(const unsigned short* __restrict__ xt,
                                                        const unsigned short* __restrict__ wpack,
                                                        float* __restrict__ out) {
    const int bid = blockIdx.x;
    const int g4 = bid & 15;
    const int cg = (bid >> 4) & 3;
    const int b = bid >> 6;
    const int x0g = cg * 128;
    const int ygBase = g4 * 4;

    const int tid = threadIdx.x;
    const int lane = tid & 63, wv = tid >> 6;
    const int n = lane & 15, g = lane >> 4;

    __shared__ unsigned char lds[10 * PITCH];

    // per-batch weight fragments (B operand), 5 chunks x 16B per lane
    half8 wf[5];
    {
        const uint4* wp = (const uint4*)wpack + (size_t)b * 5 * 64 + lane;
#pragma unroll
        for (int c5 = 0; c5 < 5; ++c5) wf[c5] = __builtin_bit_cast(half8, wp[c5 * 64]);
    }

    // static decode of this thread's 6 staging slots (e = tid + k*512 < 2600)
    int s_rr[6];        // row within the 10-row tile
    int s_ic[6];        // x_t column offset in uint4 units: clamp(ic)*2 + h
    unsigned s_lda[6];  // swizzled LDS byte address
    bool s_ok[6];
#pragma unroll
    for (int k = 0; k < 6; ++k) {
        const int e = tid + k * 512;
        const bool ok = (e < 2600);
        const int ee = ok ? e : 0;
        const int rr = ee / 260;
        const int rem = ee - rr * 260;
        const int p = rem >> 1, h = rem & 1;
        int ic = x0g + p;  ic = ic < 511 ? ic : 511;
        unsigned a = (unsigned)(rr * PITCH + p * 32 + h * 16);
        a ^= (a >> 3) & 0x30u;  // spread 32B-stride reads across banks
        s_rr[k] = rr;  s_ic[k] = ic * 2 + h;  s_lda[k] = a;  s_ok[k] = ok;
    }
    const uint4* xb = (const uint4*)xt + ((size_t)b << 19);  // 512*512 px * 2 uint4

    // per-chunk LDS read bases (same buffer every tile); +tt*512 keeps swizzle bits
    unsigned base[5];
#pragma unroll
    for (int c5 = 0; c5 < 5; ++c5) {
        const int tp = 2 * c5 + (g >> 1);
        unsigned a;
        if (tp == 9) {
            a = 0;  // padded K rows: weights are exactly 0, read safe finite data
        } else {
            const int dy = tp / 3, dx = tp - dy * 3;
            a = (unsigned)((wv + dy) * PITCH + (n + dx) * 32 + (g & 1) * 16);
            a ^= (a >> 3) & 0x30u;
        }
        base[c5] = a;
    }

    uint4 stg[6];

    // prologue: stage tile 0 (only place full staging latency is exposed)
    {
        const int y0 = ygBase * 8;
#pragma unroll
        for (int k = 0; k < 6; ++k) {
            int ir = y0 + s_rr[k];  ir = ir < 511 ? ir : 511;
            if (s_ok[k]) stg[k] = xb[((size_t)ir << 10) + s_ic[k]];
        }
#pragma unroll
        for (int k = 0; k < 6; ++k)
            if (s_ok[k]) *(uint4*)(lds + s_lda[k]) = stg[k];
    }
    __syncthreads();

    for (int t = 0; t < 4; ++t) {
        const int y0 = (ygBase + t) * 8;
        const int y = y0 + wv;

        // issue next tile's loads into registers (no wait — hides under compute)
        if (t < 3) {
            const int ny0 = y0 + 8;
#pragma unroll
            for (int k = 0; k < 6; ++k) {
                int ir = ny0 + s_rr[k];  ir = ir < 511 ? ir : 511;
                if (s_ok[k]) stg[k] = xb[((size_t)ir << 10) + s_ic[k]];
            }
        }

        // compute current tile
        const bool ymask = (y < HOUT);
        float* dst0 = out + ((size_t)(b * 16 + n) * HOUT + y) * WOUT + x0g + g * 4;
#pragma unroll
        for (int tt = 0; tt < 8; ++tt) {
            half8 xf[5];
#pragma unroll
            for (int c5 = 0; c5 < 5; ++c5)
                xf[c5] = __builtin_bit_cast(half8, *(const uint4*)(lds + (base[c5] + tt * 512)));
            f32x4 acc = {0.f, 0.f, 0.f, 0.f};
#pragma unroll
            for (int c5 = 0; c5 < 5; ++c5)
                acc = __builtin_amdgcn_mfma_f32_16x16x32_f16(xf[c5], wf[c5], acc, 0, 0, 0);
            if (ymask) {
                const int pb = x0g + tt * 16 + g * 4;
                float* dst = dst0 + tt * 16;
                if (pb + 3 < WOUT) {  // 8B-aligned always (all index terms even)
                    ((float2*)dst)[0] = make_float2(acc[0], acc[1]);
                    ((float2*)dst)[1] = make_float2(acc[2], acc[3]);
                } else {
#pragma unroll
                    for (int r = 0; r < 4; ++r)
                        if (pb + r < WOUT) dst[r] = acc[r];
                }
            }
        }

        // publish next tile into the (single) buffer
        if (t < 3) {
            __syncthreads();   // all waves done reading current tile
#pragma unroll
            for (int k = 0; k < 6; ++k)
                if (s_ok[k]) *(uint4*)(lds + s_lda[k]) = stg[k];
            __syncthreads();   // writes visible before next tile's ds_reads
        }
    }
}

// ==================== Fallback path (round-1 fp32 direct conv) =================
#define TW 128
#define TH 8
#define XW 132

__global__ __launch_bounds__(256) void pool_kernel(const float* __restrict__ x,
                                                   float* __restrict__ pooled) {
    const int bc = blockIdx.x;
    const float4* src = (const float4*)(x + ((size_t)bc << 18));
    float s = 0.f;
    for (int e = threadIdx.x; e < (HIN * WIN / 4); e += 256) {
        float4 v = src[e];
        s += (v.x + v.y) + (v.z + v.w);
    }
    __shared__ float red[256];
    red[threadIdx.x] = s;
    __syncthreads();
    for (int off = 128; off > 0; off >>= 1) {
        if (threadIdx.x < off) red[threadIdx.x] += red[threadIdx.x + off];
        __syncthreads();
    }
    if (threadIdx.x == 0) pooled[bc] = red[0] * (1.0f / (HIN * WIN));
}

__global__ __launch_bounds__(256) void attn_kernel(const float* __restrict__ pooled,
                                                   const float* __restrict__ attn_w,
                                                   const float* __restrict__ attn_b,
                                                   float* __restrict__ pi) {
    int t = blockIdx.x * 256 + threadIdx.x;
    if (t >= BATCH * 64) return;
    int b = t >> 6, g = t & 63;
    float s = attn_b[g];
#pragma unroll
    for (int c = 0; c < CH; ++c) s += pooled[b * CH + c] * attn_w[g * CH + c];
    pi[t] = 1.0f / (1.0f + expf(-s));
}

__global__ __launch_bounds__(256) void weight_kernel(const float* __restrict__ spectral,
                                                     const float* __restrict__ pi,
                                                     float* __restrict__ wbuf) {
    int idx = blockIdx.x * 256 + threadIdx.x;
    if (idx >= BATCH * CH * CH * 12) return;
    int tap = idx % 12;
    int o = (idx / 12) % CH;
    int i = (idx / 192) % CH;
    int b = idx / 3072;
    float w = 0.f;
    if (tap < 9) {
        int ki = tap / 3, kj = tap % 3;
        int r = i * 3 + ki, c = o * 3 + kj;
        float gi = -0.5f + (float)r * (1.0f / 47.0f);
        float gj = -0.5f + (float)c * (1.0f / 47.0f);
        float d2 = gi * gi + gj * gj;
        if (d2 < 0.25f) {
            int gid = (int)(sqrtf(d2) * 128.0f);
            gid = gid < 63 ? gid : 63;
            w = spectral[r * 48 + c] * pi[b * 64 + gid];
        }
    }
    wbuf[idx] = w;
}

__global__ __launch_bounds__(256) void conv_kernel(const float* __restrict__ x,
                                                   const float* __restrict__ wbuf,
                                                   float* __restrict__ out) {
    const int b = blockIdx.y;
    const int tc = blockIdx.x & 3;
    const int tr = blockIdx.x >> 2;
    __shared__ float xs[10 * XW];
    __shared__ float ws[CH * CH * 12];
    {
        const float4* src = (const float4*)(wbuf + (size_t)b * (CH * CH * 12));
        float4* dst = (float4*)ws;
        for (int e = threadIdx.x; e < 768; e += 256) dst[e] = src[e];
    }
    const int r0 = tr * TH, c0 = tc * TW;
    const int px = (threadIdx.x & 31) * 4, py = threadIdx.x >> 5;
    float acc[16][4];
#pragma unroll
    for (int o = 0; o < 16; ++o)
#pragma unroll
        for (int p = 0; p < 4; ++p) acc[o][p] = 0.f;
    for (int i = 0; i < CH; ++i) {
        __syncthreads();
        const float* xsrc = x + (((size_t)b * CH + i) << 18);
        for (int e = threadIdx.x; e < 330; e += 256) {
            int rr = e / 33;
            int c4 = (e - rr * 33) * 4;
            int ir = r0 + rr, ic = c0 + c4;
            float4 v;
            if (ir < HIN && ic + 3 < WIN) {
                v = *(const float4*)(xsrc + ((size_t)ir << 9) + ic);
            } else {
                v.x = v.y = v.z = v.w = 0.f;
                if (ir < HIN) {
                    const float* row = xsrc + ((size_t)ir << 9);
                    if (ic + 0 < WIN) v.x = row[ic + 0];
                    if (ic + 1 < WIN) v.y = row[ic + 1];
                    if (ic + 2 < WIN) v.z = row[ic + 2];
                    if (ic + 3 < WIN) v.w = row[ic + 3];
                }
            }
            *(float4*)(xs + rr * XW + c4) = v;
        }
        __syncthreads();
        float xv[3][8];
#pragma unroll
        for (int kr = 0; kr < 3; ++kr) {
            float4 a = *(const float4*)(xs + (py + kr) * XW + px);
            float4 c = *(const float4*)(xs + (py + kr) * XW + px + 4);
            xv[kr][0] = a.x; xv[kr][1] = a.y; xv[kr][2] = a.z; xv[kr][3] = a.w;
            xv[kr][4] = c.x; xv[kr][5] = c.y; xv[kr][6] = c.z; xv[kr][7] = c.w;
        }
#pragma unroll
        for (int o = 0; o < 16; ++o) {
            const float* wrow = ws + (i * 16 + o) * 12;
            float4 w0 = *(const float4*)wrow;
            float4 w1 = *(const float4*)(wrow + 4);
            float w8 = wrow[8];
#pragma unroll
            for (int p = 0; p < 4; ++p) {
                float s = acc[o][p];
                s += xv[0][p + 0] * w0.x;
                s += xv[0][p + 1] * w0.y;
                s += xv[0][p + 2] * w0.z;
                s += xv[1][p + 0] * w0.w;
                s += xv[1][p + 1] * w1.x;
                s += xv[1][p + 2] * w1.y;
                s += xv[2][p + 0] * w1.z;
                s += xv[2][p + 1] * w1.w;
                s += xv[2][p + 2] * w8;
                acc[o][p] = s;
            }
        }
    }
    const int oy = r0 + py, ox = c0 + px;
    if (oy < HOUT) {
#pragma unroll
        for (int o = 0; o < 16; ++o) {
            float* orow = out + (((size_t)(b * 16 + o)) * HOUT + oy) * WOUT + ox;
            if (ox + 3 < WOUT) {
                ((float2*)orow)[0] = make_float2(acc[o][0], acc[o][1]);
                ((float2*)orow)[1] = make_float2(acc[o][2], acc[o][3]);
            } else {
#pragma unroll
                for (int p = 0; p < 4; ++p)
                    if (ox + p < WOUT) orow[p] = acc[o][p];
            }
        }
    }
}

// ==================== launch ====================================================
extern "C" void kernel_launch(void* const* d_in, const int* in_sizes, int n_in,
                              void* d_out, int out_size, void* d_ws, size_t ws_size,
                              hipStream_t stream) {
    const float* x = (const float*)d_in[0];         // [16,16,512,512]
    const float* spectral = (const float*)d_in[1];  // [48,48]
    const float* attn_w = (const float*)d_in[2];    // [64,16]
    const float* attn_b = (const float*)d_in[3];    // [64]
    float* out = (float*)d_out;                     // [16,16,510,510]

    const size_t XT_BYTES = (size_t)16 * 512 * 512 * 16 * 2;   // 134,217,728
    const size_t PSUM_BYTES = (size_t)16 * 1024 * 16 * 4;      // 1,048,576
    const size_t WPACK_BYTES = (size_t)16 * 5 * 64 * 8 * 2;    // 81,920
    const size_t NEED = XT_BYTES + PSUM_BYTES + WPACK_BYTES;

    if (ws_size >= NEED) {
        unsigned short* xt = (unsigned short*)d_ws;
        float* psum = (float*)((char*)d_ws + XT_BYTES);
        unsigned short* wpack = (unsigned short*)((char*)d_ws + XT_BYTES + PSUM_BYTES);

        transform_kernel<<<dim3(4096), dim3(256), 0, stream>>>(x, xt, psum);
        stage2_kernel<<<dim3(16), dim3(256), 0, stream>>>(psum, attn_w, attn_b, spectral, wpack);
        conv_mfma_kernel<<<dim3(1024), dim3(512), 0, stream>>>(xt, wpack, out);
    } else {
        float* ws = (float*)d_ws;
        float* pooled = ws;
        float* pi = ws + 256;
        float* wbuf = ws + 1280;
        pool_kernel<<<dim3(BATCH * CH), dim3(256), 0, stream>>>(x, pooled);
        attn_kernel<<<dim3(4), dim3(256), 0, stream>>>(pooled, attn_w, attn_b, pi);
        weight_kernel<<<dim3((BATCH * CH * CH * 12 + 255) / 256), dim3(256), 0, stream>>>(spectral, pi, wbuf);
        conv_kernel<<<dim3(4 * 64, BATCH), dim3(256), 0, stream>>>(x, wbuf, out);
    }
}

// Round 8
// 199.202 us; speedup vs baseline: 1.2851x; 1.2851x over previous
//
#include <hip/hip_runtime.h>

// FrFDConv: per-batch dynamic 3x3 conv, B=16, 16ch->16ch, 512x512 -> 510x510 VALID.
//
// MFMA path (requires ~136 MB workspace):
//   1. transform_kernel: x fp32 NCHW -> x_t f16 NHWC + pool partials
//   2. stage2_kernel:    pooled -> sigmoid gate -> weights in MFMA B-frag layout
//   3. conv_mfma_kernel: implicit GEMM, mfma_f32_16x16x32_f16. FULL-WIDTH blocks:
//      block = 2 output rows x 510 cols x 16 ch (8 waves = 2 rows x 4 col-groups),
//      so every 128B output line is dirtied by ONE block -> kills the 1.67x
//      partial-line write amplification (WRITE 446MB vs 266 ideal, r3..r7) that
//      per-col-tile blocks caused. One-shot schedule (r7 persistent regressed).
// Fallback (small ws): round-1 fp32 direct conv.

#define BATCH 16
#define CH 16
#define HIN 512
#define WIN 512
#define HOUT 510
#define WOUT 510

typedef _Float16 half8 __attribute__((ext_vector_type(8)));
typedef float f32x4 __attribute__((ext_vector_type(4)));

// K-order kappa = 0..159 (5 chunks x 32): tap t = kappa>>4 (t=9 -> zero pad), chan i = kappa&15.
// MFMA frag (16x16x32): lane l holds k = (l>>4)*8 + j, j=0..7; A row / B col = l&15.

// ---------------- kernel 1: NHWC f16 transform + pool partials -----------------
// grid 4096 (16 b x 256), block 256; thread = 4 consecutive pixels, all 16 ch.
__global__ __launch_bounds__(256) void transform_kernel(const float* __restrict__ x,
                                                        unsigned short* __restrict__ xt,
                                                        float* __restrict__ psum) {
    const int blk = blockIdx.x;
    const int b = blk >> 8, within = blk & 255;
    const int tid = threadIdx.x;
    const int p0 = (within * 256 + tid) * 4;       // pixel base within plane
    const float* xb = x + ((size_t)b << 22);

    f32x4 v[16];
    float s[16];
#pragma unroll
    for (int c = 0; c < 16; ++c) {
        v[c] = __builtin_nontemporal_load((const f32x4*)(xb + ((size_t)c << 18) + p0));
        s[c] = (v[c][0] + v[c][1]) + (v[c][2] + v[c][3]);
    }

    union { _Float16 h[64]; uint4 q[8]; } u;
#pragma unroll
    for (int c = 0; c < 16; ++c) {
        u.h[0 * 16 + c] = (_Float16)v[c][0];
        u.h[1 * 16 + c] = (_Float16)v[c][1];
        u.h[2 * 16 + c] = (_Float16)v[c][2];
        u.h[3 * 16 + c] = (_Float16)v[c][3];
    }
    uint4* dst = (uint4*)(xt + ((size_t)((b << 18) + p0)) * 16);
#pragma unroll
    for (int k = 0; k < 8; ++k) dst[k] = u.q[k];   // cached: conv re-reads x_t

    // wave-level pool partials
#pragma unroll
    for (int c = 0; c < 16; ++c) {
        float r = s[c];
        r += __shfl_xor(r, 1);  r += __shfl_xor(r, 2);  r += __shfl_xor(r, 4);
        r += __shfl_xor(r, 8);  r += __shfl_xor(r, 16); r += __shfl_xor(r, 32);
        s[c] = r;
    }
    if ((tid & 63) == 0) {
        float* ps = psum + (size_t)(b * 1024 + within * 4 + (tid >> 6)) * 16;
#pragma unroll
        for (int c = 0; c < 16; ++c) ps[c] = s[c];
    }
}

// ---------------- kernel 2: pooled -> gate -> weight pack ----------------------
// grid 16 (one block per batch), block 256.
__global__ __launch_bounds__(256) void stage2_kernel(const float* __restrict__ psum,
                                                     const float* __restrict__ attn_w,
                                                     const float* __restrict__ attn_b,
                                                     const float* __restrict__ spectral,
                                                     unsigned short* __restrict__ wpack) {
    const int b = blockIdx.x, t = threadIdx.x;
    const int c = t & 15, m = t >> 4;
    float s = 0.f;
    for (int j = 0; j < 64; ++j) s += psum[((size_t)b * 1024 + m + j * 16) * 16 + c];
    __shared__ float red[256];
    __shared__ float pooled[16];
    __shared__ float pis[64];
    red[t] = s;
    __syncthreads();
    for (int off = 8; off; off >>= 1) {
        if (m < off) red[t] += red[t + off * 16];
        __syncthreads();
    }
    if (t < 16) pooled[t] = red[t] * (1.f / 262144.f);
    __syncthreads();
    if (t < 64) {
        float a = attn_b[t];
#pragma unroll
        for (int c2 = 0; c2 < 16; ++c2) a += pooled[c2] * attn_w[t * 16 + c2];
        pis[t] = 1.f / (1.f + expf(-a));
    }
    __syncthreads();
    for (int e = t; e < 320; e += 256) {
        const int c5 = e >> 6, lane = e & 63;
        const int o = lane & 15, g = lane >> 4;
        union { _Float16 h[8]; uint4 q; } u;
#pragma unroll
        for (int j = 0; j < 8; ++j) {
            const int kap = c5 * 32 + g * 8 + j;
            const int tp = kap >> 4, i = kap & 15;
            float wv = 0.f;
            if (tp < 9) {
                const int ki = tp / 3, kj = tp - ki * 3;
                const int r = i * 3 + ki, cc = o * 3 + kj;
                const float gi = -0.5f + (float)r * (1.f / 47.f);
                const float gj = -0.5f + (float)cc * (1.f / 47.f);
                const float d2 = gi * gi + gj * gj;
                if (d2 < 0.25f) {
                    int gid = (int)(sqrtf(d2) * 128.f);
                    gid = gid < 63 ? gid : 63;
                    wv = spectral[r * 48 + cc] * pis[gid];
                }
            }
            u.h[j] = (_Float16)wv;
        }
        *(uint4*)(wpack + ((size_t)(b * 5 + c5) * 64 + lane) * 8) = u.q;
    }
}

// ---------------- kernel 3: implicit-GEMM conv, full-width blocks --------------
// grid (255, 16): blockIdx.x = output row-pair, .y = batch. Block 512 thr/8 waves:
// wave w -> output row y0+(w>>2), cols (w&3)*128..+127. Stages input rows
// y0..y0+3 x 512 px x 16ch = 64 KB LDS (no clamps needed: rows<=511, cols<=511).
// A-frag reads wrap in-row (&16383) so masked tail pixels stay in-bounds.
#define ROWP 16384  // LDS bytes per staged input row (512 px * 32B)
__global__ __launch_bounds__(512) void conv_mfma_kernel(const unsigned short* __restrict__ xt,
                                                        const unsigned short* __restrict__ wpack,
                                                        float* __restrict__ out) {
    const int b = blockIdx.y;
    const int y0 = blockIdx.x * 2;

    const int tid = threadIdx.x;
    const int lane = tid & 63, wv = tid >> 6;
    const int n = lane & 15, g = lane >> 4;
    const int cg = wv & 3, rw = wv >> 2;
    const int y = y0 + rw;

    __shared__ unsigned char lds[4 * ROWP];   // 65536 B

    // per-batch weight fragments (B operand), 5 chunks x 16B per lane
    half8 wf[5];
    {
        const uint4* wp = (const uint4*)wpack + (size_t)b * 5 * 64 + lane;
#pragma unroll
        for (int c5 = 0; c5 < 5; ++c5) wf[c5] = __builtin_bit_cast(half8, wp[c5 * 64]);
    }

    // stage rows y0..y0+3, cols 0..511, 16 ch f16, XOR-swizzled (no clamps)
    {
        const uint4* xb = (const uint4*)xt + ((size_t)b << 19);  // 512*512 px * 2
#pragma unroll
        for (int k = 0; k < 8; ++k) {
            const int e = tid + k * 512;          // 0..4095
            const int rr = e >> 10, q = e & 1023; // row, in-row uint4 index
            const uint4 v = xb[((size_t)(y0 + rr) << 10) + q];
            unsigned a = (unsigned)(e << 4);
            a ^= (a >> 3) & 0x30u;                // swizzle (row bits untouched)
            *(uint4*)(lds + a) = v;
        }
    }
    __syncthreads();

    // per-chunk in-row byte base (unswizzled) + row base
    unsigned q0[5], rb[5];
#pragma unroll
    for (int c5 = 0; c5 < 5; ++c5) {
        const int tp = 2 * c5 + (g >> 1);
        if (tp == 9) {                            // zero-weight pad chunk
            q0[c5] = 0; rb[c5] = 0;
        } else {
            const int dy = tp / 3, dx = tp - dy * 3;
            q0[c5] = (unsigned)((cg * 128 + n + dx) * 32 + (g & 1) * 16);
            rb[c5] = (unsigned)((rw + dy) * ROWP);
        }
    }

    float* dst0 = out + ((size_t)(b * 16 + n) * HOUT + y) * WOUT + cg * 128 + g * 4;

#pragma unroll
    for (int tt = 0; tt < 8; ++tt) {
        half8 xf[5];
#pragma unroll
        for (int c5 = 0; c5 < 5; ++c5) {
            unsigned a = (q0[c5] + tt * 512u) & 16383u;  // in-row wrap (tail px)
            a ^= (a >> 3) & 0x30u;
            xf[c5] = __builtin_bit_cast(half8, *(const uint4*)(lds + (rb[c5] + a)));
        }
        f32x4 acc = {0.f, 0.f, 0.f, 0.f};
#pragma unroll
        for (int c5 = 0; c5 < 5; ++c5)
            acc = __builtin_amdgcn_mfma_f32_16x16x32_f16(xf[c5], wf[c5], acc, 0, 0, 0);
        const int pb = cg * 128 + tt * 16 + g * 4;
        float* dst = dst0 + tt * 16;
        if (pb + 3 < WOUT) {  // 8B-aligned always (all index terms even)
            ((float2*)dst)[0] = make_float2(acc[0], acc[1]);
            ((float2*)dst)[1] = make_float2(acc[2], acc[3]);
        } else {
#pragma unroll
            for (int r = 0; r < 4; ++r)
                if (pb + r < WOUT) dst[r] = acc[r];
        }
    }
}

// ==================== Fallback path (round-1 fp32 direct conv) =================
#define TW 128
#define TH 8
#define XW 132

__global__ __launch_bounds__(256) void pool_kernel(const float* __restrict__ x,
                                                   float* __restrict__ pooled) {
    const int bc = blockIdx.x;
    const float4* src = (const float4*)(x + ((size_t)bc << 18));
    float s = 0.f;
    for (int e = threadIdx.x; e < (HIN * WIN / 4); e += 256) {
        float4 v = src[e];
        s += (v.x + v.y) + (v.z + v.w);
    }
    __shared__ float red[256];
    red[threadIdx.x] = s;
    __syncthreads();
    for (int off = 128; off > 0; off >>= 1) {
        if (threadIdx.x < off) red[threadIdx.x] += red[threadIdx.x + off];
        __syncthreads();
    }
    if (threadIdx.x == 0) pooled[bc] = red[0] * (1.0f / (HIN * WIN));
}

__global__ __launch_bounds__(256) void attn_kernel(const float* __restrict__ pooled,
                                                   const float* __restrict__ attn_w,
                                                   const float* __restrict__ attn_b,
                                                   float* __restrict__ pi) {
    int t = blockIdx.x * 256 + threadIdx.x;
    if (t >= BATCH * 64) return;
    int b = t >> 6, g = t & 63;
    float s = attn_b[g];
#pragma unroll
    for (int c = 0; c < CH; ++c) s += pooled[b * CH + c] * attn_w[g * CH + c];
    pi[t] = 1.0f / (1.0f + expf(-s));
}

__global__ __launch_bounds__(256) void weight_kernel(const float* __restrict__ spectral,
                                                     const float* __restrict__ pi,
                                                     float* __restrict__ wbuf) {
    int idx = blockIdx.x * 256 + threadIdx.x;
    if (idx >= BATCH * CH * CH * 12) return;
    int tap = idx % 12;
    int o = (idx / 12) % CH;
    int i = (idx / 192) % CH;
    int b = idx / 3072;
    float w = 0.f;
    if (tap < 9) {
        int ki = tap / 3, kj = tap % 3;
        int r = i * 3 + ki, c = o * 3 + kj;
        float gi = -0.5f + (float)r * (1.0f / 47.0f);
        float gj = -0.5f + (float)c * (1.0f / 47.0f);
        float d2 = gi * gi + gj * gj;
        if (d2 < 0.25f) {
            int gid = (int)(sqrtf(d2) * 128.0f);
            gid = gid < 63 ? gid : 63;
            w = spectral[r * 48 + c] * pi[b * 64 + gid];
        }
    }
    wbuf[idx] = w;
}

__global__ __launch_bounds__(256) void conv_kernel(const float* __restrict__ x,
                                                   const float* __restrict__ wbuf,
                                                   float* __restrict__ out) {
    const int b = blockIdx.y;
    const int tc = blockIdx.x & 3;
    const int tr = blockIdx.x >> 2;
    __shared__ float xs[10 * XW];
    __shared__ float ws[CH * CH * 12];
    {
        const float4* src = (const float4*)(wbuf + (size_t)b * (CH * CH * 12));
        float4* dst = (float4*)ws;
        for (int e = threadIdx.x; e < 768; e += 256) dst[e] = src[e];
    }
    const int r0 = tr * TH, c0 = tc * TW;
    const int px = (threadIdx.x & 31) * 4, py = threadIdx.x >> 5;
    float acc[16][4];
#pragma unroll
    for (int o = 0; o < 16; ++o)
#pragma unroll
        for (int p = 0; p < 4; ++p) acc[o][p] = 0.f;
    for (int i = 0; i < CH; ++i) {
        __syncthreads();
        const float* xsrc = x + (((size_t)b * CH + i) << 18);
        for (int e = threadIdx.x; e < 330; e += 256) {
            int rr = e / 33;
            int c4 = (e - rr * 33) * 4;
            int ir = r0 + rr, ic = c0 + c4;
            float4 v;
            if (ir < HIN && ic + 3 < WIN) {
                v = *(const float4*)(xsrc + ((size_t)ir << 9) + ic);
            } else {
                v.x = v.y = v.z = v.w = 0.f;
                if (ir < HIN) {
                    const float* row = xsrc + ((size_t)ir << 9);
                    if (ic + 0 < WIN) v.x = row[ic + 0];
                    if (ic + 1 < WIN) v.y = row[ic + 1];
                    if (ic + 2 < WIN) v.z = row[ic + 2];
                    if (ic + 3 < WIN) v.w = row[ic + 3];
                }
            }
            *(float4*)(xs + rr * XW + c4) = v;
        }
        __syncthreads();
        float xv[3][8];
#pragma unroll
        for (int kr = 0; kr < 3; ++kr) {
            float4 a = *(const float4*)(xs + (py + kr) * XW + px);
            float4 c = *(const float4*)(xs + (py + kr) * XW + px + 4);
            xv[kr][0] = a.x; xv[kr][1] = a.y; xv[kr][2] = a.z; xv[kr][3] = a.w;
            xv[kr][4] = c.x; xv[kr][5] = c.y; xv[kr][6] = c.z; xv[kr][7] = c.w;
        }
#pragma unroll
        for (int o = 0; o < 16; ++o) {
            const float* wrow = ws + (i * 16 + o) * 12;
            float4 w0 = *(const float4*)wrow;
            float4 w1 = *(const float4*)(wrow + 4);
            float w8 = wrow[8];
#pragma unroll
            for (int p = 0; p < 4; ++p) {
                float s = acc[o][p];
                s += xv[0][p + 0] * w0.x;
                s += xv[0][p + 1] * w0.y;
                s += xv[0][p + 2] * w0.z;
                s += xv[1][p + 0] * w0.w;
                s += xv[1][p + 1] * w1.x;
                s += xv[1][p + 2] * w1.y;
                s += xv[2][p + 0] * w1.z;
                s += xv[2][p + 1] * w1.w;
                s += xv[2][p + 2] * w8;
                acc[o][p] = s;
            }
        }
    }
    const int oy = r0 + py, ox = c0 + px;
    if (oy < HOUT) {
#pragma unroll
        for (int o = 0; o < 16; ++o) {
            float* orow = out + (((size_t)(b * 16 + o)) * HOUT + oy) * WOUT + ox;
            if (ox + 3 < WOUT) {
                ((float2*)orow)[0] = make_float2(acc[o][0], acc[o][1]);
                ((float2*)orow)[1] = make_float2(acc[o][2], acc[o][3]);
            } else {
#pragma unroll
                for (int p = 0; p < 4; ++p)
                    if (ox + p < WOUT) orow[p] = acc[o][p];
            }
        }
    }
}

// ==================== launch ====================================================
extern "C" void kernel_launch(void* const* d_in, const int* in_sizes, int n_in,
                              void* d_out, int out_size, void* d_ws, size_t ws_size,
                              hipStream_t stream) {
    const float* x = (const float*)d_in[0];         // [16,16,512,512]
    const float* spectral = (const float*)d_in[1];  // [48,48]
    const float* attn_w = (const float*)d_in[2];    // [64,16]
    const float* attn_b = (const float*)d_in[3];    // [64]
    float* out = (float*)d_out;                     // [16,16,510,510]

    const size_t XT_BYTES = (size_t)16 * 512 * 512 * 16 * 2;   // 134,217,728
    const size_t PSUM_BYTES = (size_t)16 * 1024 * 16 * 4;      // 1,048,576
    const size_t WPACK_BYTES = (size_t)16 * 5 * 64 * 8 * 2;    // 81,920
    const size_t NEED = XT_BYTES + PSUM_BYTES + WPACK_BYTES;

    if (ws_size >= NEED) {
        unsigned short* xt = (unsigned short*)d_ws;
        float* psum = (float*)((char*)d_ws + XT_BYTES);
        unsigned short* wpack = (unsigned short*)((char*)d_ws + XT_BYTES + PSUM_BYTES);

        transform_kernel<<<dim3(4096), dim3(256), 0, stream>>>(x, xt, psum);
        stage2_kernel<<<dim3(16), dim3(256), 0, stream>>>(psum, attn_w, attn_b, spectral, wpack);
        conv_mfma_kernel<<<dim3(255, 16), dim3(512), 0, stream>>>(xt, wpack, out);
    } else {
        float* ws = (float*)d_ws;
        float* pooled = ws;
        float* pi = ws + 256;
        float* wbuf = ws + 1280;
        pool_kernel<<<dim3(BATCH * CH), dim3(256), 0, stream>>>(x, pooled);
        attn_kernel<<<dim3(4), dim3(256), 0, stream>>>(pooled, attn_w, attn_b, pi);
        weight_kernel<<<dim3((BATCH * CH * CH * 12 + 255) / 256), dim3(256), 0, stream>>>(spectral, pi, wbuf);
        conv_kernel<<<dim3(4 * 64, BATCH), dim3(256), 0, stream>>>(x, wbuf, out);
    }
}

// Round 9
// 184.436 us; speedup vs baseline: 1.3880x; 1.0801x over previous
//
#include <hip/hip_runtime.h>

// FrFDConv: per-batch dynamic 3x3 conv, B=16, 16ch->16ch, 512x512 -> 510x510 VALID.
//
// MFMA path (requires ~136 MB workspace):
//   1. transform_kernel: x fp32 NCHW -> x_t f16 NHWC via v_cvt_pk_f16_f32 pairs
//      + LDS-based pool partial reduce (replaces 96-shfl per-thread reduce)
//   2. stage2_kernel:    pooled -> sigmoid gate -> weights in MFMA B-frag layout
//   3. conv_mfma_kernel: implicit GEMM, mfma_f32_16x16x32_f16, full-width row-pair
//      blocks (write-amp fix, r8), staging via global_load_lds width=16 with
//      PRE-SWIZZLED SOURCE index (LDS dest linear; swz moved to source = same
//      involution the reads use). No VGPR round-trip in staging.
// Fallback (small ws): round-1 fp32 direct conv.

#define BATCH 16
#define CH 16
#define HIN 512
#define WIN 512
#define HOUT 510
#define WOUT 510

typedef _Float16 half8 __attribute__((ext_vector_type(8)));
typedef float f32x4 __attribute__((ext_vector_type(4)));
typedef _Float16 half2v __attribute__((ext_vector_type(2)));

// K-order kappa = 0..159 (5 chunks x 32): tap t = kappa>>4 (t=9 -> zero pad), chan i = kappa&15.
// MFMA frag (16x16x32): lane l holds k = (l>>4)*8 + j, j=0..7; A row / B col = l&15.

// ---------------- kernel 1: NHWC f16 transform + pool partials -----------------
// grid 4096 (16 b x 256), block 256; thread = 4 consecutive pixels, all 16 ch.
__global__ __launch_bounds__(256) void transform_kernel(const float* __restrict__ x,
                                                        unsigned short* __restrict__ xt,
                                                        float* __restrict__ psum) {
    const int blk = blockIdx.x;
    const int b = blk >> 8, within = blk & 255;
    const int tid = threadIdx.x;
    const int p0 = (within * 256 + tid) * 4;       // pixel base within plane
    const float* xb = x + ((size_t)b << 22);

    f32x4 v[16];
    float s[16];
#pragma unroll
    for (int c = 0; c < 16; ++c) {
        v[c] = __builtin_nontemporal_load((const f32x4*)(xb + ((size_t)c << 18) + p0));
        s[c] = (v[c][0] + v[c][1]) + (v[c][2] + v[c][3]);
    }

    // pack 4 px x 16 ch via v_cvt_pk_f16_f32 (RTZ; error budget ok: absmax<<0.715)
    union { unsigned w[32]; uint4 q[8]; } u;
#pragma unroll
    for (int m = 0; m < 4; ++m)
#pragma unroll
        for (int jj = 0; jj < 8; ++jj)
            u.w[m * 8 + jj] = __builtin_bit_cast(unsigned,
                __builtin_amdgcn_cvt_pkrtz(v[2 * jj][m], v[2 * jj + 1][m]));
    uint4* dst = (uint4*)(xt + ((size_t)((b << 18) + p0)) * 16);
#pragma unroll
    for (int k = 0; k < 8; ++k) dst[k] = u.q[k];   // cached: conv re-reads x_t

    // pool partials: LDS transpose + 16-wide partial + 4 shfl (was 96 shfl)
    __shared__ float red[16 * 256];
#pragma unroll
    for (int c = 0; c < 16; ++c) red[c * 256 + tid] = s[c];
    __syncthreads();
    const int rc = tid >> 4, rp = tid & 15;        // channel, part
    float s1 = 0.f;
#pragma unroll
    for (int j = 0; j < 16; ++j) s1 += red[rc * 256 + rp * 16 + j];
    s1 += __shfl_xor(s1, 1); s1 += __shfl_xor(s1, 2);
    s1 += __shfl_xor(s1, 4); s1 += __shfl_xor(s1, 8);
    if (rp == 0) psum[(size_t)(b * 256 + within) * 16 + rc] = s1;
}

// ---------------- kernel 2: pooled -> gate -> weight pack ----------------------
// grid 16 (one block per batch), block 256.
__global__ __launch_bounds__(256) void stage2_kernel(const float* __restrict__ psum,
                                                     const float* __restrict__ attn_w,
                                                     const float* __restrict__ attn_b,
                                                     const float* __restrict__ spectral,
                                                     unsigned short* __restrict__ wpack) {
    const int b = blockIdx.x, t = threadIdx.x;
    const int c = t & 15, m = t >> 4;              // m = 0..15
    float s = 0.f;
#pragma unroll
    for (int j = 0; j < 16; ++j) s += psum[(size_t)(b * 256 + m * 16 + j) * 16 + c];
    __shared__ float red[256];
    __shared__ float pooled[16];
    __shared__ float pis[64];
    red[t] = s;
    __syncthreads();
    for (int off = 8; off; off >>= 1) {
        if (m < off) red[t] += red[t + off * 16];
        __syncthreads();
    }
    if (t < 16) pooled[t] = red[t] * (1.f / 262144.f);
    __syncthreads();
    if (t < 64) {
        float a = attn_b[t];
#pragma unroll
        for (int c2 = 0; c2 < 16; ++c2) a += pooled[c2] * attn_w[t * 16 + c2];
        pis[t] = 1.f / (1.f + expf(-a));
    }
    __syncthreads();
    for (int e = t; e < 320; e += 256) {
        const int c5 = e >> 6, lane = e & 63;
        const int o = lane & 15, g = lane >> 4;
        union { _Float16 h[8]; uint4 q; } u;
#pragma unroll
        for (int j = 0; j < 8; ++j) {
            const int kap = c5 * 32 + g * 8 + j;
            const int tp = kap >> 4, i = kap & 15;
            float wv = 0.f;
            if (tp < 9) {
                const int ki = tp / 3, kj = tp - ki * 3;
                const int r = i * 3 + ki, cc = o * 3 + kj;
                const float gi = -0.5f + (float)r * (1.f / 47.f);
                const float gj = -0.5f + (float)cc * (1.f / 47.f);
                const float d2 = gi * gi + gj * gj;
                if (d2 < 0.25f) {
                    int gid = (int)(sqrtf(d2) * 128.f);
                    gid = gid < 63 ? gid : 63;
                    wv = spectral[r * 48 + cc] * pis[gid];
                }
            }
            u.h[j] = (_Float16)wv;
        }
        *(uint4*)(wpack + ((size_t)(b * 5 + c5) * 64 + lane) * 8) = u.q;
    }
}

// ---------------- kernel 3: implicit-GEMM conv, full-width blocks --------------
// grid (255, 16): blockIdx.x = output row-pair, .y = batch. Block 512 thr/8 waves:
// wave w -> output row y0+(w>>2), cols (w&3)*128..+127. Stages input rows
// y0..y0+3 x 512 px x 16ch = 64 KB LDS via global_load_lds (dest linear,
// swizzle applied to SOURCE index; reads apply the same involution).
#define ROWP 16384  // LDS bytes per staged input row (512 px * 32B)
__global__ __launch_bounds__(512) void conv_mfma_kernel(const unsigned short* __restrict__ xt,
                                                        const unsigned short* __restrict__ wpack,
                                                        float* __restrict__ out) {
    const int b = blockIdx.y;
    const int y0 = blockIdx.x * 2;

    const int tid = threadIdx.x;
    const int lane = tid & 63, wv = tid >> 6;
    const int n = lane & 15, g = lane >> 4;
    const int cg = wv & 3, rw = wv >> 2;
    const int y = y0 + rw;

    __shared__ uint4 ldsbuf[4096];   // 65536 B, linear dest for global_load_lds
    unsigned char* ldsb = (unsigned char*)ldsbuf;

    // per-batch weight fragments (B operand), 5 chunks x 16B per lane
    half8 wf[5];
    {
        const uint4* wp = (const uint4*)wpack + (size_t)b * 5 * 64 + lane;
#pragma unroll
        for (int c5 = 0; c5 < 5; ++c5) wf[c5] = __builtin_bit_cast(half8, wp[c5 * 64]);
    }

    // stage rows y0..y0+3 x 512 px x 16 ch: 8 x global_load_lds width=16.
    // dest uint4 slot e = k*512+tid (linear = wave-uniform base + lane*16);
    // source element e' = e ^ ((e>>3)&3)  (same involution the reads use).
    {
        const uint4* xb = (const uint4*)xt + ((size_t)b << 19);  // 512*512 px * 2
#pragma unroll
        for (int k = 0; k < 8; ++k) {
            const int e = k * 512 + tid;
            const int ep = e ^ ((e >> 3) & 3);     // row bits (>=10) untouched
            const int rr = ep >> 10, q = ep & 1023;
            __builtin_amdgcn_global_load_lds(
                (const __attribute__((address_space(1))) void*)(xb + (((size_t)(y0 + rr)) << 10) + q),
                (__attribute__((address_space(3))) void*)(&ldsbuf[e]),
                16, 0, 0);
        }
    }
    __syncthreads();

    // per-chunk in-row byte base (unswizzled) + row base
    unsigned q0[5], rb[5];
#pragma unroll
    for (int c5 = 0; c5 < 5; ++c5) {
        const int tp = 2 * c5 + (g >> 1);
        if (tp == 9) {                            // zero-weight pad chunk
            q0[c5] = 0; rb[c5] = 0;
        } else {
            const int dy = tp / 3, dx = tp - dy * 3;
            q0[c5] = (unsigned)((cg * 128 + n + dx) * 32 + (g & 1) * 16);
            rb[c5] = (unsigned)((rw + dy) * ROWP);
        }
    }

    float* dst0 = out + ((size_t)(b * 16 + n) * HOUT + y) * WOUT + cg * 128 + g * 4;

#pragma unroll
    for (int tt = 0; tt < 8; ++tt) {
        half8 xf[5];
#pragma unroll
        for (int c5 = 0; c5 < 5; ++c5) {
            unsigned a = (q0[c5] + tt * 512u) & 16383u;  // in-row wrap (tail px)
            a ^= (a >> 3) & 0x30u;
            xf[c5] = __builtin_bit_cast(half8, *(const uint4*)(ldsb + (rb[c5] + a)));
        }
        f32x4 acc = {0.f, 0.f, 0.f, 0.f};
#pragma unroll
        for (int c5 = 0; c5 < 5; ++c5)
            acc = __builtin_amdgcn_mfma_f32_16x16x32_f16(xf[c5], wf[c5], acc, 0, 0, 0);
        const int pb = cg * 128 + tt * 16 + g * 4;
        float* dst = dst0 + tt * 16;
        if (pb + 3 < WOUT) {  // 8B-aligned always (all index terms even)
            ((float2*)dst)[0] = make_float2(acc[0], acc[1]);
            ((float2*)dst)[1] = make_float2(acc[2], acc[3]);
        } else {
#pragma unroll
            for (int r = 0; r < 4; ++r)
                if (pb + r < WOUT) dst[r] = acc[r];
        }
    }
}

// ==================== Fallback path (round-1 fp32 direct conv) =================
#define TW 128
#define TH 8
#define XW 132

__global__ __launch_bounds__(256) void pool_kernel(const float* __restrict__ x,
                                                   float* __restrict__ pooled) {
    const int bc = blockIdx.x;
    const float4* src = (const float4*)(x + ((size_t)bc << 18));
    float s = 0.f;
    for (int e = threadIdx.x; e < (HIN * WIN / 4); e += 256) {
        float4 v = src[e];
        s += (v.x + v.y) + (v.z + v.w);
    }
    __shared__ float red[256];
    red[threadIdx.x] = s;
    __syncthreads();
    for (int off = 128; off > 0; off >>= 1) {
        if (threadIdx.x < off) red[threadIdx.x] += red[threadIdx.x + off];
        __syncthreads();
    }
    if (threadIdx.x == 0) pooled[bc] = red[0] * (1.0f / (HIN * WIN));
}

__global__ __launch_bounds__(256) void attn_kernel(const float* __restrict__ pooled,
                                                   const float* __restrict__ attn_w,
                                                   const float* __restrict__ attn_b,
                                                   float* __restrict__ pi) {
    int t = blockIdx.x * 256 + threadIdx.x;
    if (t >= BATCH * 64) return;
    int b = t >> 6, g = t & 63;
    float s = attn_b[g];
#pragma unroll
    for (int c = 0; c < CH; ++c) s += pooled[b * CH + c] * attn_w[g * CH + c];
    pi[t] = 1.0f / (1.0f + expf(-s));
}

__global__ __launch_bounds__(256) void weight_kernel(const float* __restrict__ spectral,
                                                     const float* __restrict__ pi,
                                                     float* __restrict__ wbuf) {
    int idx = blockIdx.x * 256 + threadIdx.x;
    if (idx >= BATCH * CH * CH * 12) return;
    int tap = idx % 12;
    int o = (idx / 12) % CH;
    int i = (idx / 192) % CH;
    int b = idx / 3072;
    float w = 0.f;
    if (tap < 9) {
        int ki = tap / 3, kj = tap % 3;
        int r = i * 3 + ki, c = o * 3 + kj;
        float gi = -0.5f + (float)r * (1.0f / 47.0f);
        float gj = -0.5f + (float)c * (1.0f / 47.0f);
        float d2 = gi * gi + gj * gj;
        if (d2 < 0.25f) {
            int gid = (int)(sqrtf(d2) * 128.0f);
            gid = gid < 63 ? gid : 63;
            w = spectral[r * 48 + c] * pi[b * 64 + gid];
        }
    }
    wbuf[idx] = w;
}

__global__ __launch_bounds__(256) void conv_kernel(const float* __restrict__ x,
                                                   const float* __restrict__ wbuf,
                                                   float* __restrict__ out) {
    const int b = blockIdx.y;
    const int tc = blockIdx.x & 3;
    const int tr = blockIdx.x >> 2;
    __shared__ float xs[10 * XW];
    __shared__ float ws[CH * CH * 12];
    {
        const float4* src = (const float4*)(wbuf + (size_t)b * (CH * CH * 12));
        float4* dst = (float4*)ws;
        for (int e = threadIdx.x; e < 768; e += 256) dst[e] = src[e];
    }
    const int r0 = tr * TH, c0 = tc * TW;
    const int px = (threadIdx.x & 31) * 4, py = threadIdx.x >> 5;
    float acc[16][4];
#pragma unroll
    for (int o = 0; o < 16; ++o)
#pragma unroll
        for (int p = 0; p < 4; ++p) acc[o][p] = 0.f;
    for (int i = 0; i < CH; ++i) {
        __syncthreads();
        const float* xsrc = x + (((size_t)b * CH + i) << 18);
        for (int e = threadIdx.x; e < 330; e += 256) {
            int rr = e / 33;
            int c4 = (e - rr * 33) * 4;
            int ir = r0 + rr, ic = c0 + c4;
            float4 v;
            if (ir < HIN && ic + 3 < WIN) {
                v = *(const float4*)(xsrc + ((size_t)ir << 9) + ic);
            } else {
                v.x = v.y = v.z = v.w = 0.f;
                if (ir < HIN) {
                    const float* row = xsrc + ((size_t)ir << 9);
                    if (ic + 0 < WIN) v.x = row[ic + 0];
                    if (ic + 1 < WIN) v.y = row[ic + 1];
                    if (ic + 2 < WIN) v.z = row[ic + 2];
                    if (ic + 3 < WIN) v.w = row[ic + 3];
                }
            }
            *(float4*)(xs + rr * XW + c4) = v;
        }
        __syncthreads();
        float xv[3][8];
#pragma unroll
        for (int kr = 0; kr < 3; ++kr) {
            float4 a = *(const float4*)(xs + (py + kr) * XW + px);
            float4 c = *(const float4*)(xs + (py + kr) * XW + px + 4);
            xv[kr][0] = a.x; xv[kr][1] = a.y; xv[kr][2] = a.z; xv[kr][3] = a.w;
            xv[kr][4] = c.x; xv[kr][5] = c.y; xv[kr][6] = c.z; xv[kr][7] = c.w;
        }
#pragma unroll
        for (int o = 0; o < 16; ++o) {
            const float* wrow = ws + (i * 16 + o) * 12;
            float4 w0 = *(const float4*)wrow;
            float4 w1 = *(const float4*)(wrow + 4);
            float w8 = wrow[8];
#pragma unroll
            for (int p = 0; p < 4; ++p) {
                float s = acc[o][p];
                s += xv[0][p + 0] * w0.x;
                s += xv[0][p + 1] * w0.y;
                s += xv[0][p + 2] * w0.z;
                s += xv[1][p + 0] * w0.w;
                s += xv[1][p + 1] * w1.x;
                s += xv[1][p + 2] * w1.y;
                s += xv[2][p + 0] * w1.z;
                s += xv[2][p + 1] * w1.w;
                s += xv[2][p + 2] * w8;
                acc[o][p] = s;
            }
        }
    }
    const int oy = r0 + py, ox = c0 + px;
    if (oy < HOUT) {
#pragma unroll
        for (int o = 0; o < 16; ++o) {
            float* orow = out + (((size_t)(b * 16 + o)) * HOUT + oy) * WOUT + ox;
            if (ox + 3 < WOUT) {
                ((float2*)orow)[0] = make_float2(acc[o][0], acc[o][1]);
                ((float2*)orow)[1] = make_float2(acc[o][2], acc[o][3]);
            } else {
#pragma unroll
                for (int p = 0; p < 4; ++p)
                    if (ox + p < WOUT) orow[p] = acc[o][p];
            }
        }
    }
}

// ==================== launch ====================================================
extern "C" void kernel_launch(void* const* d_in, const int* in_sizes, int n_in,
                              void* d_out, int out_size, void* d_ws, size_t ws_size,
                              hipStream_t stream) {
    const float* x = (const float*)d_in[0];         // [16,16,512,512]
    const float* spectral = (const float*)d_in[1];  // [48,48]
    const float* attn_w = (const float*)d_in[2];    // [64,16]
    const float* attn_b = (const float*)d_in[3];    // [64]
    float* out = (float*)d_out;                     // [16,16,510,510]

    const size_t XT_BYTES = (size_t)16 * 512 * 512 * 16 * 2;   // 134,217,728
    const size_t PSUM_BYTES = (size_t)16 * 1024 * 16 * 4;      // 1,048,576 (256 KB used)
    const size_t WPACK_BYTES = (size_t)16 * 5 * 64 * 8 * 2;    // 81,920
    const size_t NEED = XT_BYTES + PSUM_BYTES + WPACK_BYTES;

    if (ws_size >= NEED) {
        unsigned short* xt = (unsigned short*)d_ws;
        float* psum = (float*)((char*)d_ws + XT_BYTES);
        unsigned short* wpack = (unsigned short*)((char*)d_ws + XT_BYTES + PSUM_BYTES);

        transform_kernel<<<dim3(4096), dim3(256), 0, stream>>>(x, xt, psum);
        stage2_kernel<<<dim3(16), dim3(256), 0, stream>>>(psum, attn_w, attn_b, spectral, wpack);
        conv_mfma_kernel<<<dim3(255, 16), dim3(512), 0, stream>>>(xt, wpack, out);
    } else {
        float* ws = (float*)d_ws;
        float* pooled = ws;
        float* pi = ws + 256;
        float* wbuf = ws + 1280;
        pool_kernel<<<dim3(BATCH * CH), dim3(256), 0, stream>>>(x, pooled);
        attn_kernel<<<dim3(4), dim3(256), 0, stream>>>(pooled, attn_w, attn_b, pi);
        weight_kernel<<<dim3((BATCH * CH * CH * 12 + 255) / 256), dim3(256), 0, stream>>>(spectral, pi, wbuf);
        conv_kernel<<<dim3(4 * 64, BATCH), dim3(256), 0, stream>>>(x, wbuf, out);
    }
}